// Round 5
// baseline (50.080 us; speedup 1.0000x reference)
//
#include <hip/hip_runtime.h>
#include <stdint.h>

// ChunkMasker: mask is input-independent (jax.random.key(1)), bit-exact
// (absmax 0) since R0 with jax_threefry_partitionable semantics.
// R1: fused RNG+scan (chunk-union + binary search), mask-skipped reads.
// R2: frame-per-block apply (block-uniform predicate) — neutral.
// R3: cached x loads (LLC-resident across replays) + NT stores: -6 us.
// R4: 16 frames per block, 16 independent load/store pairs per thread
// (256 B in flight), 3004 blocks instead of 48063 — attack latency/ILP,
// not bandwidth (HBM write side is only at ~3.6 TB/s).

#define B_ 32
#define T_ 1500
#define D_ 768
#define G_ 1500            // guard budget = 4 * num_to_mask
#define NUM_TO_MASK 375
#define NWORDS 47          // ceil(1500/32)
#define NCHUNK ((G_ + 63) / 64)
#define NX (B_*T_*D_)      // 36864000
#define NMASK (B_*T_)      // 48000
#define NMASK4 (NMASK/4)   // 12000
#define FR 16              // frames per block
#define NBLK_MAIN (NMASK / FR)          // 3000
#define NBLK_TAIL ((NMASK4 + FR*192 - 1) / (FR*192))  // 4
#define NF4 (FR * 192)     // 3072 f4 per block

typedef float f4 __attribute__((ext_vector_type(4)));

__host__ __device__ static inline void tf2x32(uint32_t ka, uint32_t kb,
                                              uint32_t x0, uint32_t x1,
                                              uint32_t &o0, uint32_t &o1) {
  uint32_t kc = ka ^ kb ^ 0x1BD11BDAu;
#define TFR(r) { x0 += x1; x1 = ((x1 << (r)) | (x1 >> (32 - (r)))); x1 ^= x0; }
  x0 += ka; x1 += kb;
  TFR(13) TFR(15) TFR(26) TFR(6)   x0 += kb; x1 += kc + 1u;
  TFR(17) TFR(29) TFR(16) TFR(24)  x0 += kc; x1 += ka + 2u;
  TFR(13) TFR(15) TFR(26) TFR(6)   x0 += ka; x1 += kb + 3u;
  TFR(17) TFR(29) TFR(16) TFR(24)  x0 += kb; x1 += kc + 4u;
  TFR(13) TFR(15) TFR(26) TFR(6)   x0 += kc; x1 += ka + 5u;
#undef TFR
  o0 = x0; o1 = x1;
}

__device__ static inline int wave_sum64(int v) {
  for (int s = 1; s < 64; s <<= 1) v += __shfl_xor(v, s);
  return v;
}

// One block (one wave) per batch element. Fused RNG + order-independent scan
// (verified bit-exact R1). Chunk-union trial via LDS atomicOr; binary search
// for the crossing attempt inside the crossing chunk.
__global__ void __launch_bounds__(64)
scan_kernel(uint32_t* __restrict__ bits,
            uint32_t k1b0, uint32_t k1b1,
            uint32_t k2a0, uint32_t k2a1,
            uint32_t k2b0, uint32_t k2b1) {
  const int b = blockIdx.x;
  const int l = threadIdx.x;
  __shared__ uint32_t u[NWORDS];   // committed union
  __shared__ uint32_t t[NWORDS];   // trial union
  if (l < NWORDS) u[l] = 0u;
  __syncthreads();
  bool done = false;
  for (int chunk = 0; chunk < NCHUNK && !done; ++chunk) {
    const int g = chunk * 64 + l;
    const bool valid = (g < G_);
    uint32_t m0 = 0u, m1 = 0u;
    int w0 = 0, w1 = 0;
    if (valid) {
      const uint32_t f = (uint32_t)(g * B_ + b);
      uint32_t a0, a1;
      tf2x32(k1b0, k1b1, 0u, f, a0, a1);
      const uint32_t len = 2u + ((a0 ^ a1) & 3u);      // randint [2,6)
      tf2x32(k2a0, k2a1, 0u, f, a0, a1);
      const uint32_t hb = a0 ^ a1;
      tf2x32(k2b0, k2b1, 0u, f, a0, a1);
      const uint32_t lb = a0 ^ a1;
      const uint32_t span = (uint32_t)T_ - len;
      uint32_t mm = 65536u % span;
      mm = (mm * mm) % span;
      const uint32_t start = ((hb % span) * mm + (lb % span)) % span;
      const uint32_t end = start + len;                // <= 1500
      w0 = (int)(start >> 5);
      w1 = (int)((end - 1u) >> 5);
      const int sh = (int)(start & 31u);
      const int n0 = min((int)len, 32 - sh);           // 1..5
      m0 = ((1u << n0) - 1u) << sh;
      if (w1 != w0) m1 = (1u << ((int)len - n0)) - 1u;
    }
    if (l < NWORDS) t[l] = u[l];
    __syncthreads();
    if (valid) { atomicOr(&t[w0], m0); if (w1 != w0) atomicOr(&t[w1], m1); }
    __syncthreads();
    int tot = wave_sum64((l < NWORDS) ? __popc(t[l]) : 0);
    if (tot < NUM_TO_MASK) {
      __syncthreads();
      if (l < NWORDS) u[l] = t[l];
      __syncthreads();
      continue;
    }
    int lo = 0;
    int hi = min(63, G_ - chunk * 64 - 1);
    while (lo < hi) {
      const int mid = (lo + hi) >> 1;
      __syncthreads();
      if (l < NWORDS) t[l] = u[l];
      __syncthreads();
      if (valid && l <= mid) { atomicOr(&t[w0], m0); if (w1 != w0) atomicOr(&t[w1], m1); }
      __syncthreads();
      tot = wave_sum64((l < NWORDS) ? __popc(t[l]) : 0);
      if (tot >= NUM_TO_MASK) hi = mid; else lo = mid + 1;
    }
    __syncthreads();
    if (l < NWORDS) t[l] = u[l];
    __syncthreads();
    if (valid && l <= lo) { atomicOr(&t[w0], m0); if (w1 != w0) atomicOr(&t[w1], m1); }
    __syncthreads();
    if (l < NWORDS) u[l] = t[l];
    done = true;
  }
  __syncthreads();
  if (l < NWORDS) bits[b * NWORDS + l] = u[l];
}

// Batched apply: block < 3000 handles 16 consecutive frames (192 threads,
// thread tid owns f4 tid of each frame). Mask bits pre-gathered (L1-hit),
// 16 independent cached loads issued up-front (masked frames skipped,
// block-uniform predicate), then 16 NT stores. Tail blocks: float mask.
__global__ void __launch_bounds__(192)
apply_kernel(const f4* __restrict__ x4, f4* __restrict__ out4,
             const uint32_t* __restrict__ bits) {
  const int blk = blockIdx.x;
  const int tid = threadIdx.x;
  if (blk < NBLK_MAIN) {
    const int f0 = blk * FR;
    uint32_t mbit[FR];
#pragma unroll
    for (int fi = 0; fi < FR; ++fi) {
      const int bt = f0 + fi;
      const int b = bt / T_;                  // magic-mul
      const int t = bt - b * T_;
      mbit[fi] = (bits[b * NWORDS + (t >> 5)] >> (t & 31)) & 1u;
    }
    const size_t base = (size_t)blk * NF4 + tid;
    f4 v[FR];
#pragma unroll
    for (int fi = 0; fi < FR; ++fi) {
      v[fi] = (f4)(0.f);
      if (!mbit[fi]) v[fi] = x4[base + fi * 192];     // cached (LLC)
    }
#pragma unroll
    for (int fi = 0; fi < FR; ++fi)
      __builtin_nontemporal_store(v[fi], &out4[base + fi * 192]);
  } else {
    const int i0 = (blk - NBLK_MAIN) * NF4 + tid;
#pragma unroll
    for (int fi = 0; fi < FR; ++fi) {
      const int i = i0 + fi * 192;            // tail f4 index
      if (i < NMASK4) {
        const int f0q = i * 4;                // b*1500 + t0, t0 % 4 == 0
        const int b = f0q / T_;
        const int t0 = f0q - b * T_;
        const uint32_t w = bits[b * NWORDS + (t0 >> 5)];  // t0&31 <= 28
        f4 v;
        v.x = ((w >> ((t0 + 0) & 31)) & 1u) ? 1.f : 0.f;
        v.y = ((w >> ((t0 + 1) & 31)) & 1u) ? 1.f : 0.f;
        v.z = ((w >> ((t0 + 2) & 31)) & 1u) ? 1.f : 0.f;
        v.w = ((w >> ((t0 + 3) & 31)) & 1u) ? 1.f : 0.f;
        __builtin_nontemporal_store(v, &out4[(size_t)(NX / 4) + i]);
      }
    }
  }
}

extern "C" void kernel_launch(void* const* d_in, const int* in_sizes, int n_in,
                              void* d_out, int out_size, void* d_ws, size_t ws_size,
                              hipStream_t stream) {
  const float* x = (const float*)d_in[0];
  float* out = (float*)d_out;
  uint32_t* bits = (uint32_t*)d_ws;           // 6016 B

  // Host-side key derivation (partitionable fold-like split), verified R0:
  // root = key(1) = (0,1); k1 = cipher(root,(0,0)), k2 = cipher(root,(0,1))
  // lens  : k1b = cipher(k1,(0,1))   (k1a unused: span=4 -> multiplier 0)
  // starts: k2a = cipher(k2,(0,0)), k2b = cipher(k2,(0,1))
  uint32_t k1_0, k1_1, k2_0, k2_1;
  tf2x32(0u, 1u, 0u, 0u, k1_0, k1_1);
  tf2x32(0u, 1u, 0u, 1u, k2_0, k2_1);
  uint32_t k1b0, k1b1, k2a0, k2a1, k2b0, k2b1;
  tf2x32(k1_0, k1_1, 0u, 1u, k1b0, k1b1);
  tf2x32(k2_0, k2_1, 0u, 0u, k2a0, k2a1);
  tf2x32(k2_0, k2_1, 0u, 1u, k2b0, k2b1);

  hipLaunchKernelGGL(scan_kernel, dim3(B_), dim3(64), 0, stream,
                     bits, k1b0, k1b1, k2a0, k2a1, k2b0, k2b1);
  hipLaunchKernelGGL(apply_kernel, dim3(NBLK_MAIN + NBLK_TAIL), dim3(192), 0,
                     stream, (const f4*)x, (f4*)out, bits);
}

// Round 6
// 48.112 us; speedup vs baseline: 1.0409x; 1.0409x over previous
//
#include <hip/hip_runtime.h>
#include <stdint.h>

// ChunkMasker: mask is input-independent (jax.random.key(1)), bit-exact
// (absmax 0) since R0 with jax_threefry_partitionable semantics.
// R1: fused RNG+scan (chunk-union + binary search), mask-skipped reads.
// R2: frame-per-block apply (block-uniform predicate) — neutral.
// R3: cached x loads + NT stores: 46.5 us.
// R4: FR=16 deep batching — REGRESSED (50.1): traded TLP for too much ILP.
// R5: revert to R3 base; wave-per-frame apply (ILP=3, 256-thr blocks,
// 12000 blocks) + mask tail folded into scan_kernel.

#define B_ 32
#define T_ 1500
#define D_ 768
#define G_ 1500            // guard budget = 4 * num_to_mask
#define NUM_TO_MASK 375
#define NWORDS 47          // ceil(1500/32)
#define NCHUNK ((G_ + 63) / 64)
#define NX (B_*T_*D_)      // 36864000
#define NMASK (B_*T_)      // 48000
#define NFRAME (B_*T_)     // 48000 frames
#define TAILF4 375         // f4 per batch row of the float mask tail

typedef float f4 __attribute__((ext_vector_type(4)));

__host__ __device__ static inline void tf2x32(uint32_t ka, uint32_t kb,
                                              uint32_t x0, uint32_t x1,
                                              uint32_t &o0, uint32_t &o1) {
  uint32_t kc = ka ^ kb ^ 0x1BD11BDAu;
#define TFR(r) { x0 += x1; x1 = ((x1 << (r)) | (x1 >> (32 - (r)))); x1 ^= x0; }
  x0 += ka; x1 += kb;
  TFR(13) TFR(15) TFR(26) TFR(6)   x0 += kb; x1 += kc + 1u;
  TFR(17) TFR(29) TFR(16) TFR(24)  x0 += kc; x1 += ka + 2u;
  TFR(13) TFR(15) TFR(26) TFR(6)   x0 += ka; x1 += kb + 3u;
  TFR(17) TFR(29) TFR(16) TFR(24)  x0 += kb; x1 += kc + 4u;
  TFR(13) TFR(15) TFR(26) TFR(6)   x0 += kc; x1 += ka + 5u;
#undef TFR
  o0 = x0; o1 = x1;
}

__device__ static inline int wave_sum64(int v) {
  for (int s = 1; s < 64; s <<= 1) v += __shfl_xor(v, s);
  return v;
}

// One block (one wave) per batch element. Fused RNG + order-independent scan
// (verified bit-exact since R1). Chunk-union trial via LDS atomicOr; binary
// search for the crossing attempt inside the crossing chunk. Also writes the
// float mask tail for its batch row (bits already in LDS).
__global__ void __launch_bounds__(64)
scan_kernel(uint32_t* __restrict__ bits, f4* __restrict__ tail,
            uint32_t k1b0, uint32_t k1b1,
            uint32_t k2a0, uint32_t k2a1,
            uint32_t k2b0, uint32_t k2b1) {
  const int b = blockIdx.x;
  const int l = threadIdx.x;
  __shared__ uint32_t u[NWORDS];   // committed union
  __shared__ uint32_t t[NWORDS];   // trial union
  if (l < NWORDS) u[l] = 0u;
  __syncthreads();
  bool done = false;
  for (int chunk = 0; chunk < NCHUNK && !done; ++chunk) {
    const int g = chunk * 64 + l;
    const bool valid = (g < G_);
    uint32_t m0 = 0u, m1 = 0u;
    int w0 = 0, w1 = 0;
    if (valid) {
      const uint32_t f = (uint32_t)(g * B_ + b);
      uint32_t a0, a1;
      tf2x32(k1b0, k1b1, 0u, f, a0, a1);
      const uint32_t len = 2u + ((a0 ^ a1) & 3u);      // randint [2,6)
      tf2x32(k2a0, k2a1, 0u, f, a0, a1);
      const uint32_t hb = a0 ^ a1;
      tf2x32(k2b0, k2b1, 0u, f, a0, a1);
      const uint32_t lb = a0 ^ a1;
      const uint32_t span = (uint32_t)T_ - len;
      uint32_t mm = 65536u % span;
      mm = (mm * mm) % span;
      const uint32_t start = ((hb % span) * mm + (lb % span)) % span;
      const uint32_t end = start + len;                // <= 1500
      w0 = (int)(start >> 5);
      w1 = (int)((end - 1u) >> 5);
      const int sh = (int)(start & 31u);
      const int n0 = min((int)len, 32 - sh);           // 1..5
      m0 = ((1u << n0) - 1u) << sh;
      if (w1 != w0) m1 = (1u << ((int)len - n0)) - 1u;
    }
    if (l < NWORDS) t[l] = u[l];
    __syncthreads();
    if (valid) { atomicOr(&t[w0], m0); if (w1 != w0) atomicOr(&t[w1], m1); }
    __syncthreads();
    int tot = wave_sum64((l < NWORDS) ? __popc(t[l]) : 0);
    if (tot < NUM_TO_MASK) {
      __syncthreads();
      if (l < NWORDS) u[l] = t[l];
      __syncthreads();
      continue;
    }
    int lo = 0;
    int hi = min(63, G_ - chunk * 64 - 1);
    while (lo < hi) {
      const int mid = (lo + hi) >> 1;
      __syncthreads();
      if (l < NWORDS) t[l] = u[l];
      __syncthreads();
      if (valid && l <= mid) { atomicOr(&t[w0], m0); if (w1 != w0) atomicOr(&t[w1], m1); }
      __syncthreads();
      tot = wave_sum64((l < NWORDS) ? __popc(t[l]) : 0);
      if (tot >= NUM_TO_MASK) hi = mid; else lo = mid + 1;
    }
    __syncthreads();
    if (l < NWORDS) t[l] = u[l];
    __syncthreads();
    if (valid && l <= lo) { atomicOr(&t[w0], m0); if (w1 != w0) atomicOr(&t[w1], m1); }
    __syncthreads();
    if (l < NWORDS) u[l] = t[l];
    done = true;
  }
  __syncthreads();
  if (l < NWORDS) bits[b * NWORDS + l] = u[l];
  // float mask tail for batch row b: 375 f4 (t0 = i*4 <= 1496, single word)
  for (int i = l; i < TAILF4; i += 64) {
    const int t0 = i * 4;
    const uint32_t w = u[t0 >> 5];
    f4 v;
    v.x = ((w >> ((t0 + 0) & 31)) & 1u) ? 1.f : 0.f;
    v.y = ((w >> ((t0 + 1) & 31)) & 1u) ? 1.f : 0.f;
    v.z = ((w >> ((t0 + 2) & 31)) & 1u) ? 1.f : 0.f;
    v.w = ((w >> ((t0 + 3) & 31)) & 1u) ? 1.f : 0.f;
    __builtin_nontemporal_store(v, &tail[b * TAILF4 + i]);
  }
}

// Wave-per-frame apply: block = 256 threads = 4 waves = 4 frames. Lane l of
// wave wid handles f4s {l, l+64, l+128} of frame blk*4+wid — 3 coalesced
// 1KiB wave-transactions, ILP 3. Predicate wave-uniform; masked frames never
// touch x. Cached loads, NT stores.
__global__ void __launch_bounds__(256)
apply_kernel(const f4* __restrict__ x4, f4* __restrict__ out4,
             const uint32_t* __restrict__ bits) {
  const int wid = threadIdx.x >> 6;
  const int l = threadIdx.x & 63;
  const int fr = blockIdx.x * 4 + wid;        // frame index
  const int b = fr / T_;                      // magic-mul
  const int t = fr - b * T_;
  const uint32_t w = bits[b * NWORDS + (t >> 5)];
  const size_t base = (size_t)fr * (D_ / 4) + l;
  f4 v0 = (f4)(0.f), v1 = (f4)(0.f), v2 = (f4)(0.f);
  if (!((w >> (t & 31)) & 1u)) {
    v0 = x4[base];
    v1 = x4[base + 64];
    v2 = x4[base + 128];
  }
  __builtin_nontemporal_store(v0, &out4[base]);
  __builtin_nontemporal_store(v1, &out4[base + 64]);
  __builtin_nontemporal_store(v2, &out4[base + 128]);
}

extern "C" void kernel_launch(void* const* d_in, const int* in_sizes, int n_in,
                              void* d_out, int out_size, void* d_ws, size_t ws_size,
                              hipStream_t stream) {
  const float* x = (const float*)d_in[0];
  float* out = (float*)d_out;
  uint32_t* bits = (uint32_t*)d_ws;           // 6016 B
  f4* tail = (f4*)(out + NX);                 // float mask region

  // Host-side key derivation (partitionable fold-like split), verified R0:
  // root = key(1) = (0,1); k1 = cipher(root,(0,0)), k2 = cipher(root,(0,1))
  // lens  : k1b = cipher(k1,(0,1))   (k1a unused: span=4 -> multiplier 0)
  // starts: k2a = cipher(k2,(0,0)), k2b = cipher(k2,(0,1))
  uint32_t k1_0, k1_1, k2_0, k2_1;
  tf2x32(0u, 1u, 0u, 0u, k1_0, k1_1);
  tf2x32(0u, 1u, 0u, 1u, k2_0, k2_1);
  uint32_t k1b0, k1b1, k2a0, k2a1, k2b0, k2b1;
  tf2x32(k1_0, k1_1, 0u, 1u, k1b0, k1b1);
  tf2x32(k2_0, k2_1, 0u, 0u, k2a0, k2a1);
  tf2x32(k2_0, k2_1, 0u, 1u, k2b0, k2b1);

  hipLaunchKernelGGL(scan_kernel, dim3(B_), dim3(64), 0, stream,
                     bits, tail, k1b0, k1b1, k2a0, k2a1, k2b0, k2b1);
  hipLaunchKernelGGL(apply_kernel, dim3(NFRAME / 4), dim3(256), 0, stream,
                     (const f4*)x, (f4*)out, bits);
}